// Round 1
// 880.040 us; speedup vs baseline: 1.1131x; 1.1131x over previous
//
#include <hip/hip_runtime.h>
#include <stdint.h>

#define E_    64
#define D_    1024
#define SMAX_ 1536
#define B_    2048
#define EPS_  1e-5f

typedef __attribute__((ext_vector_type(8))) __bf16 bf16x8;
typedef __attribute__((ext_vector_type(4))) float f32x4;

__device__ __forceinline__ unsigned int f2bf(float f) {      // RNE
  unsigned int u = __float_as_uint(f);
  u += 0x7fffu + ((u >> 16) & 1u);
  return u >> 16;
}
__device__ __forceinline__ unsigned int f2bf_rn(float f) {   // round-half-up, 2 ops
  return (__float_as_uint(f) + 0x8000u) >> 16;
}
// dword = {bf16(b) << 16 | bf16(a)}, half-up rounding, 3 VALU ops total
__device__ __forceinline__ unsigned int pk2bf(float a, float b) {
  return __builtin_amdgcn_perm(__float_as_uint(b) + 0x8000u,
                               __float_as_uint(a) + 0x8000u, 0x07060302u);
}
__device__ __forceinline__ float bf2f(unsigned int s) {
  return __uint_as_float(s << 16);
}
__device__ __forceinline__ int expert_size(int e) {
  return (int)(1024.0 * (0.5 + (double)e / 63.0));
}

#define GLDS16(gp, lp) \
  __builtin_amdgcn_global_load_lds( \
      (const __attribute__((address_space(1))) unsigned int*)(const void*)(gp), \
      (__attribute__((address_space(3))) unsigned int*)(void*)(lp), 16, 0, 0)

// ---------------------------------------------------------------- router
__global__ void __launch_bounds__(256) router_kernel(
    const float* __restrict__ x, const float* __restrict__ Wr,
    const float* __restrict__ br, int* __restrict__ topi,
    float* __restrict__ topw, unsigned short* __restrict__ xbf)
{
  __shared__ float xs[D_];
  __shared__ double red[256];
  const int b = blockIdx.x, t = threadIdx.x;

  const float4* xr = (const float4*)(x + (size_t)b * D_);
  uint2* xbr = (uint2*)(xbf + (size_t)b * D_);
  for (int i = t; i < D_ / 4; i += 256) {
    float4 v = xr[i];
    xs[i * 4 + 0] = v.x; xs[i * 4 + 1] = v.y;
    xs[i * 4 + 2] = v.z; xs[i * 4 + 3] = v.w;
    uint2 p;
    p.x = pk2bf(v.x, v.y);
    p.y = pk2bf(v.z, v.w);
    xbr[i] = p;
  }
  __syncthreads();

  const int e = t & 63, q = t >> 6;
  const float* wp = Wr + (size_t)(q * 256) * E_ + e;
  double acc = 0.0;
#pragma unroll 8
  for (int d = 0; d < 256; d++)
    acc += (double)xs[q * 256 + d] * (double)wp[(size_t)d * E_];
  red[t] = acc;
  __syncthreads();

  if (t < 64) {
    double lg = red[t] + red[t + 64] + red[t + 128] + red[t + 192] + (double)br[t];
    double v = lg;
    double sel_v[4]; int sel_i[4];
#pragma unroll
    for (int k = 0; k < 4; k++) {
      double mv = v; int mi = t;
      for (int off = 32; off > 0; off >>= 1) {
        double ov = __shfl_down(mv, off);
        int    oi = __shfl_down(mi, off);
        if (ov > mv || (ov == mv && oi < mi)) { mv = ov; mi = oi; }
      }
      mv = __shfl(mv, 0); mi = __shfl(mi, 0);
      sel_v[k] = mv; sel_i[k] = mi;
      if (t == mi) v = -1e300;
    }
    if (t == 0) {
      double mx = sel_v[0], s = 0.0, w[4];
#pragma unroll
      for (int k = 0; k < 4; k++) { w[k] = exp(sel_v[k] - mx); s += w[k]; }
#pragma unroll
      for (int k = 0; k < 4; k++) {
        topi[b * 4 + k] = sel_i[k];
        topw[b * 4 + k] = (float)(w[k] / s);
      }
    }
  }
}

// ---------------------------------------------------------------- setup
__global__ void __launch_bounds__(256) setup_kernel(
    const int* __restrict__ topi, const float* __restrict__ topw,
    int* __restrict__ counts, int* __restrict__ offs,
    int* __restrict__ tlist, float* __restrict__ wlist,
    int* __restrict__ slot_of)
{
  __shared__ int cnt[E_], base[E_], cur[E_];
  const int t = threadIdx.x;
  if (t < E_) cnt[t] = 0;
  __syncthreads();
  for (int i = t; i < B_ * 4; i += 256) atomicAdd(&cnt[topi[i]], 1);
  __syncthreads();
  if (t == 0) {
    int s = 0;
    for (int e = 0; e < E_; e++) { base[e] = s; s += cnt[e]; }
  }
  __syncthreads();
  if (t < E_) { counts[t] = cnt[t]; offs[t] = base[t]; cur[t] = 0; }
  __syncthreads();
  for (int i = t; i < B_ * 4; i += 256) {
    int e = topi[i];
    int p = atomicAdd(&cur[e], 1);
    int slot = base[e] + p;
    tlist[slot] = i >> 2;
    wlist[slot] = topw[i];
    slot_of[i] = slot;
  }
}

// ---------------------------------------------------------------- gemm1
// h[slot, s] = relu(BN1(x[token] @ W1[e])), bf16 out. 192x128 tile, BK=32.
// M=192 so the m0 loop runs once for ~all experts (Ne ~ 128 +- 11): no full
// W-strip re-read for tails. Grid (e, s_tile): id = e + 64*stile, 64%8==0 so
// all tiles of expert e land on XCD e%8 (W/L2 locality).
__global__ void __launch_bounds__(256, 2) gemm1_kernel(
    const unsigned short* __restrict__ xbf, const float* __restrict__ W1,
    const float* __restrict__ b1, const float* __restrict__ g1,
    const float* __restrict__ be1, const float* __restrict__ m1,
    const float* __restrict__ v1,
    const int* __restrict__ counts, const int* __restrict__ offs,
    const int* __restrict__ tlist, unsigned short* __restrict__ hbuf)
{
  const int e = blockIdx.x;
  const int s0 = blockIdx.y * 128;
  const int Se = expert_size(e);
  if (s0 >= Se) return;
  const int Ne = counts[e];
  if (Ne == 0) return;
  const int off = offs[e];

  __shared__ short lsA[192 * 32];          // [row][k], 16B chunks XOR-swizzled
  __shared__ unsigned int lsB[128 * 17];   // [n][k/2], stride 17 dwords
  __shared__ float lsAl[128], lsBt[128];

  const int t = threadIdx.x, lane = t & 63, wv = t >> 6;
  const int wm = wv >> 1, wn = wv & 1;

  if (t < 128) {
    int s = s0 + t;
    float al = g1[e * SMAX_ + s] * rsqrtf(v1[e * SMAX_ + s] + EPS_);
    lsAl[t] = al;
    lsBt[t] = (b1[e * SMAX_ + s] - m1[e * SMAX_ + s]) * al + be1[e * SMAX_ + s];
  }

  // ---- B staging mapping: thread covers n in {2c, 2c+1}, k rows j*8..j*8+7
  const int c = lane, j = wv;
  const float* Wb = W1 + (size_t)e * D_ * SMAX_ + s0 + 2 * c;
  unsigned int* wEven = lsB + (2 * c) * 17 + 4 * j;
  unsigned int* wOdd  = lsB + (2 * c + 1) * 17 + 4 * j;

  // ---- A staging: glds, source chunk swizzled so slot c' holds chunk c'^(row&3)
  const int cs = (((lane & 3) ^ ((lane >> 2) & 3)) << 3);  // shorts
  short* aDst0 = lsA + (wv * 48) * 32;
  short* aDst1 = lsA + (wv * 48 + 16) * 32;
  short* aDst2 = lsA + (wv * 48 + 32) * 32;

  // fragment read offsets (k-loop invariant)
  const int aro = ((lane >> 4) ^ (lane & 3)) << 3;         // swizzled chunk, shorts
  const int arow = wm * 96 + (lane & 15);
  const int nbase = wn * 64 + (lane & 15);
  const int bq = (lane >> 4) * 4;

  for (int m0 = 0; m0 < Ne; m0 += 192) {
    int row0 = m0 + wv * 48 + (lane >> 2);
    int sl0 = off + row0;          sl0 = sl0 < 8191 ? sl0 : 8191;
    int sl1 = off + row0 + 16;     sl1 = sl1 < 8191 ? sl1 : 8191;
    int sl2 = off + row0 + 32;     sl2 = sl2 < 8191 ? sl2 : 8191;
    const unsigned short* aSrc0 = xbf + (size_t)tlist[sl0] * D_ + cs;
    const unsigned short* aSrc1 = xbf + (size_t)tlist[sl1] * D_ + cs;
    const unsigned short* aSrc2 = xbf + (size_t)tlist[sl2] * D_ + cs;

    f32x4 acc[6][4] = {};
    float2 f[8];
#pragma unroll
    for (int i = 0; i < 8; i++)
      f[i] = *(const float2*)(Wb + (size_t)(j * 8 + i) * SMAX_);

    for (int k0 = 0; k0 < D_; k0 += 32) {
      __syncthreads();
      // regs -> LDS (B), 2-way banks (free)
      uint2 p0, p1;
      p0.x = pk2bf(f[0].x, f[1].x); p0.y = pk2bf(f[2].x, f[3].x);
      p1.x = pk2bf(f[4].x, f[5].x); p1.y = pk2bf(f[6].x, f[7].x);
      *(uint2*)(wEven)     = p0;
      *(uint2*)(wEven + 2) = p1;
      wOdd[0] = pk2bf(f[0].y, f[1].y);
      wOdd[1] = pk2bf(f[2].y, f[3].y);
      wOdd[2] = pk2bf(f[4].y, f[5].y);
      wOdd[3] = pk2bf(f[6].y, f[7].y);
      // A tile via glds (16B/lane)
      GLDS16(aSrc0 + k0, aDst0);
      GLDS16(aSrc1 + k0, aDst1);
      GLDS16(aSrc2 + k0, aDst2);
      __syncthreads();

      // prefetch next B strip into regs (hidden under MFMA)
      if (k0 + 32 < D_) {
#pragma unroll
        for (int i = 0; i < 8; i++)
          f[i] = *(const float2*)(Wb + (size_t)(k0 + 32 + j * 8 + i) * SMAX_);
      }

      bf16x8 af[6], bfr[4];
#pragma unroll
      for (int mt = 0; mt < 6; mt++)
        af[mt] = *(const bf16x8*)(lsA + (arow + mt * 16) * 32 + aro);
#pragma unroll
      for (int nt = 0; nt < 4; nt++) {
        int bb = (nbase + nt * 16) * 17 + bq;
        unsigned int r0 = lsB[bb], r1 = lsB[bb + 1], r2 = lsB[bb + 2], r3 = lsB[bb + 3];
        __attribute__((ext_vector_type(4))) unsigned int raw = {r0, r1, r2, r3};
        bfr[nt] = __builtin_bit_cast(bf16x8, raw);
      }
#pragma unroll
      for (int mt = 0; mt < 6; mt++)
#pragma unroll
        for (int nt = 0; nt < 4; nt++)
          acc[mt][nt] = __builtin_amdgcn_mfma_f32_16x16x32_bf16(af[mt], bfr[nt], acc[mt][nt], 0, 0, 0);
    }

    // epilogue: BN1 + relu -> bf16. C layout: col=lane&15, row=(lane>>4)*4+r
#pragma unroll
    for (int mt = 0; mt < 6; mt++)
#pragma unroll
      for (int nt = 0; nt < 4; nt++) {
        int nc = wn * 64 + nt * 16 + (lane & 15);
        float al = lsAl[nc], bt = lsBt[nc];
#pragma unroll
        for (int r = 0; r < 4; r++) {
          int m = m0 + wm * 96 + mt * 16 + (lane >> 4) * 4 + r;
          if (m < Ne) {
            float v = acc[mt][nt][r] * al + bt;
            v = v > 0.f ? v : 0.f;
            hbuf[(size_t)(off + m) * SMAX_ + s0 + nc] = (unsigned short)f2bf_rn(v);
          }
        }
      }
  }
}

// ---------------------------------------------------------------- gemm2
// Grid (e, d_tile): all 8 d-tiles of expert e -> same XCD, so the hbuf
// window for e is fetched once per XCD (likely L2-warm from gemm1).
__global__ void __launch_bounds__(256, 2) gemm2_kernel(
    const unsigned short* __restrict__ hbuf, const float* __restrict__ W2,
    const float* __restrict__ b2, const float* __restrict__ g2,
    const float* __restrict__ be2, const float* __restrict__ m2,
    const float* __restrict__ v2,
    const int* __restrict__ counts, const int* __restrict__ offs,
    const float* __restrict__ wlist, unsigned short* __restrict__ ybuf)
{
  const int e = blockIdx.x;
  const int d0 = blockIdx.y * 128;
  const int Se = expert_size(e);
  const int Ne = counts[e];
  if (Ne == 0) return;
  const int off = offs[e];
  const int Kp = (Se + 31) & ~31;

  __shared__ short lsA[192 * 32];
  __shared__ unsigned int lsB[128 * 17];
  __shared__ float lsAl[128], lsBt[128];

  const int t = threadIdx.x, lane = t & 63, wv = t >> 6;
  const int wm = wv >> 1, wn = wv & 1;

  if (t < 128) {
    int d = d0 + t;
    float al = g2[e * D_ + d] * rsqrtf(v2[e * D_ + d] + EPS_);
    lsAl[t] = al;
    lsBt[t] = (b2[e * D_ + d] - m2[e * D_ + d]) * al + be2[e * D_ + d];
  }

  const int c = lane, j = wv;
  const float* Wb = W2 + (size_t)e * SMAX_ * D_ + d0 + 2 * c;
  unsigned int* wEven = lsB + (2 * c) * 17 + 4 * j;
  unsigned int* wOdd  = lsB + (2 * c + 1) * 17 + 4 * j;

  const int cs = (((lane & 3) ^ ((lane >> 2) & 3)) << 3);
  short* aDst0 = lsA + (wv * 48) * 32;
  short* aDst1 = lsA + (wv * 48 + 16) * 32;
  short* aDst2 = lsA + (wv * 48 + 32) * 32;

  const int aro = ((lane >> 4) ^ (lane & 3)) << 3;
  const int arow = wm * 96 + (lane & 15);
  const int nbase = wn * 64 + (lane & 15);
  const int bq = (lane >> 4) * 4;

  for (int m0 = 0; m0 < Ne; m0 += 192) {
    int row0 = m0 + wv * 48 + (lane >> 2);
    int sl0 = off + row0;          sl0 = sl0 < 8191 ? sl0 : 8191;
    int sl1 = off + row0 + 16;     sl1 = sl1 < 8191 ? sl1 : 8191;
    int sl2 = off + row0 + 32;     sl2 = sl2 < 8191 ? sl2 : 8191;
    const unsigned short* aSrc0 = hbuf + (size_t)sl0 * SMAX_ + cs;
    const unsigned short* aSrc1 = hbuf + (size_t)sl1 * SMAX_ + cs;
    const unsigned short* aSrc2 = hbuf + (size_t)sl2 * SMAX_ + cs;

    f32x4 acc[6][4] = {};
    float2 f[8];
#pragma unroll
    for (int i = 0; i < 8; i++)
      f[i] = *(const float2*)(Wb + (size_t)(j * 8 + i) * D_);

    for (int k0 = 0; k0 < Kp; k0 += 32) {
      __syncthreads();
      uint2 p0, p1;
      p0.x = pk2bf(f[0].x, f[1].x); p0.y = pk2bf(f[2].x, f[3].x);
      p1.x = pk2bf(f[4].x, f[5].x); p1.y = pk2bf(f[6].x, f[7].x);
      *(uint2*)(wEven)     = p0;
      *(uint2*)(wEven + 2) = p1;
      wOdd[0] = pk2bf(f[0].y, f[1].y);
      wOdd[1] = pk2bf(f[2].y, f[3].y);
      wOdd[2] = pk2bf(f[4].y, f[5].y);
      wOdd[3] = pk2bf(f[6].y, f[7].y);
      GLDS16(aSrc0 + k0, aDst0);
      GLDS16(aSrc1 + k0, aDst1);
      GLDS16(aSrc2 + k0, aDst2);
      __syncthreads();

      if (k0 + 32 < Kp) {
#pragma unroll
        for (int i = 0; i < 8; i++)
          f[i] = *(const float2*)(Wb + (size_t)(k0 + 32 + j * 8 + i) * D_);
      }

      bf16x8 af[6], bfr[4];
#pragma unroll
      for (int mt = 0; mt < 6; mt++)
        af[mt] = *(const bf16x8*)(lsA + (arow + mt * 16) * 32 + aro);
#pragma unroll
      for (int nt = 0; nt < 4; nt++) {
        int bb = (nbase + nt * 16) * 17 + bq;
        unsigned int r0 = lsB[bb], r1 = lsB[bb + 1], r2 = lsB[bb + 2], r3 = lsB[bb + 3];
        __attribute__((ext_vector_type(4))) unsigned int raw = {r0, r1, r2, r3};
        bfr[nt] = __builtin_bit_cast(bf16x8, raw);
      }
#pragma unroll
      for (int mt = 0; mt < 6; mt++)
#pragma unroll
        for (int nt = 0; nt < 4; nt++)
          acc[mt][nt] = __builtin_amdgcn_mfma_f32_16x16x32_bf16(af[mt], bfr[nt], acc[mt][nt], 0, 0, 0);
    }

#pragma unroll
    for (int mt = 0; mt < 6; mt++)
#pragma unroll
      for (int nt = 0; nt < 4; nt++) {
        int nc = wn * 64 + nt * 16 + (lane & 15);
        float al = lsAl[nc], bt = lsBt[nc];
#pragma unroll
        for (int r = 0; r < 4; r++) {
          int m = m0 + wm * 96 + mt * 16 + (lane >> 4) * 4 + r;
          if (m < Ne) {
            float wr = wlist[off + m];
            float v = acc[mt][nt][r] * al + bt;
            ybuf[(size_t)(off + m) * D_ + d0 + nc] = (unsigned short)f2bf_rn(wr * v);
          }
        }
      }
  }
}

// ---------------------------------------------------------------- gather
__global__ void __launch_bounds__(256) gather_kernel(
    const float* __restrict__ x, const unsigned short* __restrict__ ybuf,
    const int* __restrict__ slot_of, float* __restrict__ out)
{
  const int b = blockIdx.x, t = threadIdx.x;
  int s[4];
#pragma unroll
  for (int k = 0; k < 4; k++) s[k] = slot_of[b * 4 + k];

  float4 xv = ((const float4*)(x + (size_t)b * D_))[t];
  float r0 = xv.x, r1 = xv.y, r2 = xv.z, r3 = xv.w;
#pragma unroll
  for (int k = 0; k < 4; k++) {
    uint2 p = ((const uint2*)(ybuf + (size_t)s[k] * D_))[t];
    r0 += bf2f(p.x & 0xffffu); r1 += bf2f(p.x >> 16);
    r2 += bf2f(p.y & 0xffffu); r3 += bf2f(p.y >> 16);
  }
  float4 o; o.x = r0; o.y = r1; o.z = r2; o.w = r3;
  ((float4*)(out + (size_t)b * D_))[t] = o;
}

// ---------------------------------------------------------------- launch
extern "C" void kernel_launch(void* const* d_in, const int* in_sizes, int n_in,
                              void* d_out, int out_size, void* d_ws, size_t ws_size,
                              hipStream_t stream)
{
  const float* x   = (const float*)d_in[0];
  const float* W1  = (const float*)d_in[1];
  const float* b1  = (const float*)d_in[2];
  const float* g1  = (const float*)d_in[3];
  const float* be1 = (const float*)d_in[4];
  const float* m1  = (const float*)d_in[5];
  const float* v1  = (const float*)d_in[6];
  const float* W2  = (const float*)d_in[7];
  const float* b2  = (const float*)d_in[8];
  const float* g2  = (const float*)d_in[9];
  const float* be2 = (const float*)d_in[10];
  const float* m2  = (const float*)d_in[11];
  const float* v2  = (const float*)d_in[12];
  const float* Wr  = (const float*)d_in[13];
  const float* br  = (const float*)d_in[14];
  float* out = (float*)d_out;

  char* ws = (char*)d_ws;
  int*            topi    = (int*)(ws + 0);
  float*          topw    = (float*)(ws + 32768);
  int*            slot_of = (int*)(ws + 65536);
  int*            tlist   = (int*)(ws + 98304);
  float*          wlist   = (float*)(ws + 131072);
  int*            counts  = (int*)(ws + 163840);
  int*            offs    = (int*)(ws + 164096);
  unsigned short* xbf     = (unsigned short*)(ws + 196608);
  unsigned short* hbuf    = (unsigned short*)(ws + 4390912);
  unsigned short* ybuf    = (unsigned short*)(ws + 29556736);

  router_kernel<<<dim3(B_), dim3(256), 0, stream>>>(x, Wr, br, topi, topw, xbf);
  setup_kernel<<<dim3(1), dim3(256), 0, stream>>>(topi, topw, counts, offs, tlist, wlist, slot_of);
  gemm1_kernel<<<dim3(E_, 12), dim3(256), 0, stream>>>(xbf, W1, b1, g1, be1, m1, v1,
                                                       counts, offs, tlist, hbuf);
  gemm2_kernel<<<dim3(E_, 8), dim3(256), 0, stream>>>(hbuf, W2, b2, g2, be2, m2, v2,
                                                      counts, offs, wlist, ybuf);
  gather_kernel<<<dim3(B_), dim3(256), 0, stream>>>(x, ybuf, slot_of, out);
}

// Round 2
// 864.943 us; speedup vs baseline: 1.1325x; 1.0175x over previous
//
#include <hip/hip_runtime.h>
#include <stdint.h>

#define E_    64
#define D_    1024
#define SMAX_ 1536
#define B_    2048
#define EPS_  1e-5f

typedef __attribute__((ext_vector_type(8))) __bf16 bf16x8;
typedef __attribute__((ext_vector_type(4))) float f32x4;

__device__ __forceinline__ unsigned int f2bf_rn(float f) {   // round-half-up, 2 ops
  return (__float_as_uint(f) + 0x8000u) >> 16;
}
// dword = {bf16(b) << 16 | bf16(a)}, half-up rounding, 3 VALU ops total
__device__ __forceinline__ unsigned int pk2bf(float a, float b) {
  return __builtin_amdgcn_perm(__float_as_uint(b) + 0x8000u,
                               __float_as_uint(a) + 0x8000u, 0x07060302u);
}
__device__ __forceinline__ float bf2f(unsigned int s) {
  return __uint_as_float(s << 16);
}
__device__ __forceinline__ int expert_size(int e) {
  return (int)(1024.0 * (0.5 + (double)e / 63.0));
}

#define GLDS16(gp, lp) \
  __builtin_amdgcn_global_load_lds( \
      (const __attribute__((address_space(1))) unsigned int*)(const void*)(gp), \
      (__attribute__((address_space(3))) unsigned int*)(void*)(lp), 16, 0, 0)

// pack 8 float2 f32 W-strip regs -> bf16 LDS (two n-columns per thread)
#define PACKB(dE, dO, F) do { \
  uint2 _p0, _p1; \
  _p0.x = pk2bf(F[0].x, F[1].x); _p0.y = pk2bf(F[2].x, F[3].x); \
  _p1.x = pk2bf(F[4].x, F[5].x); _p1.y = pk2bf(F[6].x, F[7].x); \
  *(uint2*)(dE) = _p0; *(uint2*)((dE) + 2) = _p1; \
  (dO)[0] = pk2bf(F[0].y, F[1].y); (dO)[1] = pk2bf(F[2].y, F[3].y); \
  (dO)[2] = pk2bf(F[4].y, F[5].y); (dO)[3] = pk2bf(F[6].y, F[7].y); \
} while (0)

// issue 8 global_load_dwordx2 of W strip `strip` (8 vmem ops)
#define LOADF(F, strip, STRIDE) do { \
  _Pragma("unroll") \
  for (int _i = 0; _i < 8; _i++) \
    F[_i] = *(const float2*)(Wb + (size_t)((strip) * 32 + j * 8 + _i) * (STRIDE)); \
} while (0)

// read fragments from buffer b (literal), wait LDS, fence, 24 MFMA
#define STEP_COMPUTE(b) do { \
  bf16x8 af[6], bfr[4]; \
  _Pragma("unroll") \
  for (int mt = 0; mt < 6; mt++) \
    af[mt] = *(const bf16x8*)(&lsA[b][(arow + mt * 16) * 32 + aro]); \
  _Pragma("unroll") \
  for (int nt = 0; nt < 4; nt++) { \
    int bb = (nbase + nt * 16) * 17 + bq; \
    unsigned int r0 = lsB[b][bb], r1 = lsB[b][bb + 1]; \
    unsigned int r2 = lsB[b][bb + 2], r3 = lsB[b][bb + 3]; \
    __attribute__((ext_vector_type(4))) unsigned int raw = {r0, r1, r2, r3}; \
    bfr[nt] = __builtin_bit_cast(bf16x8, raw); \
  } \
  asm volatile("s_waitcnt lgkmcnt(0)" ::: "memory"); \
  __builtin_amdgcn_sched_barrier(0); \
  _Pragma("unroll") \
  for (int mt = 0; mt < 6; mt++) \
    _Pragma("unroll") \
    for (int nt = 0; nt < 4; nt++) \
      acc[mt][nt] = __builtin_amdgcn_mfma_f32_16x16x32_bf16(af[mt], bfr[nt], acc[mt][nt], 0, 0, 0); \
} while (0)

// counted-vmcnt sync: leave the 8 newest W-loads in flight (steady state),
// drain fully only in the pipeline tail. One raw barrier per k-step.
#define STEP_SYNC(deep) do { \
  if (deep) asm volatile("s_waitcnt vmcnt(8)" ::: "memory"); \
  else      asm volatile("s_waitcnt vmcnt(0)" ::: "memory"); \
  __builtin_amdgcn_sched_barrier(0); \
  __builtin_amdgcn_s_barrier(); \
} while (0)

// ---------------------------------------------------------------- router
__global__ void __launch_bounds__(256) router_kernel(
    const float* __restrict__ x, const float* __restrict__ Wr,
    const float* __restrict__ br, int* __restrict__ topi,
    float* __restrict__ topw, unsigned short* __restrict__ xbf)
{
  __shared__ float xs[D_];
  __shared__ double red[256];
  const int b = blockIdx.x, t = threadIdx.x;

  const float4* xr = (const float4*)(x + (size_t)b * D_);
  uint2* xbr = (uint2*)(xbf + (size_t)b * D_);
  for (int i = t; i < D_ / 4; i += 256) {
    float4 v = xr[i];
    xs[i * 4 + 0] = v.x; xs[i * 4 + 1] = v.y;
    xs[i * 4 + 2] = v.z; xs[i * 4 + 3] = v.w;
    uint2 p;
    p.x = pk2bf(v.x, v.y);
    p.y = pk2bf(v.z, v.w);
    xbr[i] = p;
  }
  __syncthreads();

  const int e = t & 63, q = t >> 6;
  const float* wp = Wr + (size_t)(q * 256) * E_ + e;
  double acc = 0.0;
#pragma unroll 8
  for (int d = 0; d < 256; d++)
    acc += (double)xs[q * 256 + d] * (double)wp[(size_t)d * E_];
  red[t] = acc;
  __syncthreads();

  if (t < 64) {
    double lg = red[t] + red[t + 64] + red[t + 128] + red[t + 192] + (double)br[t];
    double v = lg;
    double sel_v[4]; int sel_i[4];
#pragma unroll
    for (int k = 0; k < 4; k++) {
      double mv = v; int mi = t;
      for (int off = 32; off > 0; off >>= 1) {
        double ov = __shfl_down(mv, off);
        int    oi = __shfl_down(mi, off);
        if (ov > mv || (ov == mv && oi < mi)) { mv = ov; mi = oi; }
      }
      mv = __shfl(mv, 0); mi = __shfl(mi, 0);
      sel_v[k] = mv; sel_i[k] = mi;
      if (t == mi) v = -1e300;
    }
    if (t == 0) {
      double mx = sel_v[0], s = 0.0, w[4];
#pragma unroll
      for (int k = 0; k < 4; k++) { w[k] = exp(sel_v[k] - mx); s += w[k]; }
#pragma unroll
      for (int k = 0; k < 4; k++) {
        topi[b * 4 + k] = sel_i[k];
        topw[b * 4 + k] = (float)(w[k] / s);
      }
    }
  }
}

// ---------------------------------------------------------------- setup
__global__ void __launch_bounds__(1024) setup_kernel(
    const int* __restrict__ topi, const float* __restrict__ topw,
    int* __restrict__ counts, int* __restrict__ offs,
    int* __restrict__ tlist, float* __restrict__ wlist,
    int* __restrict__ slot_of)
{
  __shared__ int cnt[E_], base[E_], cur[E_];
  const int t = threadIdx.x;
  if (t < E_) cnt[t] = 0;
  __syncthreads();
  for (int i = t; i < B_ * 4; i += 1024) atomicAdd(&cnt[topi[i]], 1);
  __syncthreads();
  if (t == 0) {
    int s = 0;
    for (int e = 0; e < E_; e++) { base[e] = s; s += cnt[e]; }
  }
  __syncthreads();
  if (t < E_) { counts[t] = cnt[t]; offs[t] = base[t]; cur[t] = 0; }
  __syncthreads();
  for (int i = t; i < B_ * 4; i += 1024) {
    int e = topi[i];
    int p = atomicAdd(&cur[e], 1);
    int slot = base[e] + p;
    tlist[slot] = i >> 2;
    wlist[slot] = topw[i];
    slot_of[i] = slot;
  }
}

// ---------------------------------------------------------------- gemm1
// 192x128 tile, BK=32, double-buffered LDS (A and B), ONE raw barrier per
// k-step, counted vmcnt(8): the 8 W-strip loads for step k+3 stay in flight
// across the barrier (T3/T4). W prefetch distance = 3 k-steps (~3x step
// time >> 900cy HBM latency). Grid (e, s_tile): XCD e%8 locality.
__global__ void __launch_bounds__(256, 2) gemm1_kernel(
    const unsigned short* __restrict__ xbf, const float* __restrict__ W1,
    const float* __restrict__ b1, const float* __restrict__ g1,
    const float* __restrict__ be1, const float* __restrict__ m1,
    const float* __restrict__ v1,
    const int* __restrict__ counts, const int* __restrict__ offs,
    const int* __restrict__ tlist, unsigned short* __restrict__ hbuf)
{
  const int e = blockIdx.x;
  const int s0 = blockIdx.y * 128;
  const int Se = expert_size(e);
  if (s0 >= Se) return;
  const int Ne = counts[e];
  if (Ne == 0) return;
  const int off = offs[e];

  __shared__ short lsA[2][192 * 32];          // [buf][row][k], chunks XOR-swizzled
  __shared__ unsigned int lsB[2][128 * 17];   // [buf][n][k/2], stride 17 dwords
  __shared__ float lsAl[128], lsBt[128];

  const int t = threadIdx.x, lane = t & 63, wv = t >> 6;
  const int wm = wv >> 1, wn = wv & 1;

  if (t < 128) {
    int s = s0 + t;
    float al = g1[e * SMAX_ + s] * rsqrtf(v1[e * SMAX_ + s] + EPS_);
    lsAl[t] = al;
    lsBt[t] = (b1[e * SMAX_ + s] - m1[e * SMAX_ + s]) * al + be1[e * SMAX_ + s];
  }

  // B staging mapping: thread covers n in {2c, 2c+1}, k rows j*8..j*8+7
  const int c = lane, j = wv;
  const float* Wb = W1 + (size_t)e * D_ * SMAX_ + s0 + 2 * c;
  unsigned int* wE0 = &lsB[0][(2 * c) * 17 + 4 * j];
  unsigned int* wO0 = &lsB[0][(2 * c + 1) * 17 + 4 * j];
  unsigned int* wE1 = &lsB[1][(2 * c) * 17 + 4 * j];
  unsigned int* wO1 = &lsB[1][(2 * c + 1) * 17 + 4 * j];

  // A staging: glds, source chunk swizzled so slot c' holds chunk c'^(row&3)
  const int cs = (((lane & 3) ^ ((lane >> 2) & 3)) << 3);  // shorts
  short* aD00 = &lsA[0][(wv * 48) * 32];
  short* aD01 = &lsA[0][(wv * 48 + 16) * 32];
  short* aD02 = &lsA[0][(wv * 48 + 32) * 32];
  short* aD10 = &lsA[1][(wv * 48) * 32];
  short* aD11 = &lsA[1][(wv * 48 + 16) * 32];
  short* aD12 = &lsA[1][(wv * 48 + 32) * 32];

  // fragment read offsets (k-loop invariant)
  const int aro = ((lane >> 4) ^ (lane & 3)) << 3;
  const int arow = wm * 96 + (lane & 15);
  const int nbase = wn * 64 + (lane & 15);
  const int bq = (lane >> 4) * 4;

  for (int m0 = 0; m0 < Ne; m0 += 192) {
    int row0 = m0 + wv * 48 + (lane >> 2);
    int sl0 = off + row0;          sl0 = sl0 < 8191 ? sl0 : 8191;
    int sl1 = off + row0 + 16;     sl1 = sl1 < 8191 ? sl1 : 8191;
    int sl2 = off + row0 + 32;     sl2 = sl2 < 8191 ? sl2 : 8191;
    const unsigned short* aSrc0 = xbf + (size_t)tlist[sl0] * D_ + cs;
    const unsigned short* aSrc1 = xbf + (size_t)tlist[sl1] * D_ + cs;
    const unsigned short* aSrc2 = xbf + (size_t)tlist[sl2] * D_ + cs;

    f32x4 acc[6][4] = {};
    float2 fA[8], fB[8];

    // ---- prologue: B[0]=strip0, A[0]=strip0, fB=strip1 (ready), fA=strip2 (in flight)
    LOADF(fA, 0, SMAX_);
    LOADF(fB, 1, SMAX_);
    PACKB(wE0, wO0, fA);                       // compiler waits fA loads
    GLDS16(aSrc0, aD00); GLDS16(aSrc1, aD01); GLDS16(aSrc2, aD02);
    __builtin_amdgcn_sched_barrier(0);         // pin glds before next issues
    LOADF(fA, 2, SMAX_);
    asm volatile("s_waitcnt vmcnt(8)" ::: "memory");   // drain fB+glds, leave fA
    asm volatile("s_waitcnt lgkmcnt(0)" ::: "memory");
    __builtin_amdgcn_sched_barrier(0);
    __builtin_amdgcn_s_barrier();

    for (int x = 0; x < 32; x += 2) {
      // even step x: compute strip x from buf0; stage strip x+1 -> buf1; issue strip x+3
      PACKB(wE1, wO1, fB);
      GLDS16(aSrc0 + (x + 1) * 32, aD10);
      GLDS16(aSrc1 + (x + 1) * 32, aD11);
      GLDS16(aSrc2 + (x + 1) * 32, aD12);
      __builtin_amdgcn_sched_barrier(0);
      if (x + 3 < 32) LOADF(fB, x + 3, SMAX_);
      STEP_COMPUTE(0);
      STEP_SYNC(x + 3 < 32);
      // odd step x+1: compute strip x+1 from buf1; stage strip x+2 -> buf0; issue strip x+4
      if (x + 2 < 32) {
        PACKB(wE0, wO0, fA);
        GLDS16(aSrc0 + (x + 2) * 32, aD00);
        GLDS16(aSrc1 + (x + 2) * 32, aD01);
        GLDS16(aSrc2 + (x + 2) * 32, aD02);
        __builtin_amdgcn_sched_barrier(0);
        if (x + 4 < 32) LOADF(fA, x + 4, SMAX_);
      }
      STEP_COMPUTE(1);
      STEP_SYNC(x + 4 < 32);
    }

    // epilogue: BN1 + relu -> bf16. C layout: col=lane&15, row=(lane>>4)*4+r
#pragma unroll
    for (int mt = 0; mt < 6; mt++)
#pragma unroll
      for (int nt = 0; nt < 4; nt++) {
        int nc = wn * 64 + nt * 16 + (lane & 15);
        float al = lsAl[nc], bt = lsBt[nc];
#pragma unroll
        for (int r = 0; r < 4; r++) {
          int m = m0 + wm * 96 + mt * 16 + (lane >> 4) * 4 + r;
          if (m < Ne) {
            float v = acc[mt][nt][r] * al + bt;
            v = v > 0.f ? v : 0.f;
            hbuf[(size_t)(off + m) * SMAX_ + s0 + nc] = (unsigned short)f2bf_rn(v);
          }
        }
      }
  }
}

// ---------------------------------------------------------------- gemm2
// Same pipelined structure; K padded to 64 (W2 pad rows are exact zeros by
// construction; hbuf pad cols are written 0 by gemm1). Grid (e, d_tile).
__global__ void __launch_bounds__(256, 2) gemm2_kernel(
    const unsigned short* __restrict__ hbuf, const float* __restrict__ W2,
    const float* __restrict__ b2, const float* __restrict__ g2,
    const float* __restrict__ be2, const float* __restrict__ m2,
    const float* __restrict__ v2,
    const int* __restrict__ counts, const int* __restrict__ offs,
    const float* __restrict__ wlist, unsigned short* __restrict__ ybuf)
{
  const int e = blockIdx.x;
  const int d0 = blockIdx.y * 128;
  const int Se = expert_size(e);
  const int Ne = counts[e];
  if (Ne == 0) return;
  const int off = offs[e];
  const int Kp64 = (Se + 63) & ~63;
  const int NSTEP = Kp64 >> 5;                 // even, >= 16

  __shared__ short lsA[2][192 * 32];
  __shared__ unsigned int lsB[2][128 * 17];
  __shared__ float lsAl[128], lsBt[128];

  const int t = threadIdx.x, lane = t & 63, wv = t >> 6;
  const int wm = wv >> 1, wn = wv & 1;

  if (t < 128) {
    int d = d0 + t;
    float al = g2[e * D_ + d] * rsqrtf(v2[e * D_ + d] + EPS_);
    lsAl[t] = al;
    lsBt[t] = (b2[e * D_ + d] - m2[e * D_ + d]) * al + be2[e * D_ + d];
  }

  const int c = lane, j = wv;
  const float* Wb = W2 + (size_t)e * SMAX_ * D_ + d0 + 2 * c;
  unsigned int* wE0 = &lsB[0][(2 * c) * 17 + 4 * j];
  unsigned int* wO0 = &lsB[0][(2 * c + 1) * 17 + 4 * j];
  unsigned int* wE1 = &lsB[1][(2 * c) * 17 + 4 * j];
  unsigned int* wO1 = &lsB[1][(2 * c + 1) * 17 + 4 * j];

  const int cs = (((lane & 3) ^ ((lane >> 2) & 3)) << 3);
  short* aD00 = &lsA[0][(wv * 48) * 32];
  short* aD01 = &lsA[0][(wv * 48 + 16) * 32];
  short* aD02 = &lsA[0][(wv * 48 + 32) * 32];
  short* aD10 = &lsA[1][(wv * 48) * 32];
  short* aD11 = &lsA[1][(wv * 48 + 16) * 32];
  short* aD12 = &lsA[1][(wv * 48 + 32) * 32];

  const int aro = ((lane >> 4) ^ (lane & 3)) << 3;
  const int arow = wm * 96 + (lane & 15);
  const int nbase = wn * 64 + (lane & 15);
  const int bq = (lane >> 4) * 4;

  for (int m0 = 0; m0 < Ne; m0 += 192) {
    int row0 = m0 + wv * 48 + (lane >> 2);
    int sl0 = off + row0;          sl0 = sl0 < 8191 ? sl0 : 8191;
    int sl1 = off + row0 + 16;     sl1 = sl1 < 8191 ? sl1 : 8191;
    int sl2 = off + row0 + 32;     sl2 = sl2 < 8191 ? sl2 : 8191;
    const unsigned short* aSrc0 = hbuf + (size_t)sl0 * SMAX_ + cs;
    const unsigned short* aSrc1 = hbuf + (size_t)sl1 * SMAX_ + cs;
    const unsigned short* aSrc2 = hbuf + (size_t)sl2 * SMAX_ + cs;

    f32x4 acc[6][4] = {};
    float2 fA[8], fB[8];

    LOADF(fA, 0, D_);
    LOADF(fB, 1, D_);
    PACKB(wE0, wO0, fA);
    GLDS16(aSrc0, aD00); GLDS16(aSrc1, aD01); GLDS16(aSrc2, aD02);
    __builtin_amdgcn_sched_barrier(0);
    LOADF(fA, 2, D_);
    asm volatile("s_waitcnt vmcnt(8)" ::: "memory");
    asm volatile("s_waitcnt lgkmcnt(0)" ::: "memory");
    __builtin_amdgcn_sched_barrier(0);
    __builtin_amdgcn_s_barrier();

    for (int x = 0; x < NSTEP; x += 2) {
      PACKB(wE1, wO1, fB);
      GLDS16(aSrc0 + (x + 1) * 32, aD10);
      GLDS16(aSrc1 + (x + 1) * 32, aD11);
      GLDS16(aSrc2 + (x + 1) * 32, aD12);
      __builtin_amdgcn_sched_barrier(0);
      if (x + 3 < NSTEP) LOADF(fB, x + 3, D_);
      STEP_COMPUTE(0);
      STEP_SYNC(x + 3 < NSTEP);
      if (x + 2 < NSTEP) {
        PACKB(wE0, wO0, fA);
        GLDS16(aSrc0 + (x + 2) * 32, aD00);
        GLDS16(aSrc1 + (x + 2) * 32, aD01);
        GLDS16(aSrc2 + (x + 2) * 32, aD02);
        __builtin_amdgcn_sched_barrier(0);
        if (x + 4 < NSTEP) LOADF(fA, x + 4, D_);
      }
      STEP_COMPUTE(1);
      STEP_SYNC(x + 4 < NSTEP);
    }

#pragma unroll
    for (int mt = 0; mt < 6; mt++)
#pragma unroll
      for (int nt = 0; nt < 4; nt++) {
        int nc = wn * 64 + nt * 16 + (lane & 15);
        float al = lsAl[nc], bt = lsBt[nc];
#pragma unroll
        for (int r = 0; r < 4; r++) {
          int m = m0 + wm * 96 + mt * 16 + (lane >> 4) * 4 + r;
          if (m < Ne) {
            float wr = wlist[off + m];
            float v = acc[mt][nt][r] * al + bt;
            ybuf[(size_t)(off + m) * D_ + d0 + nc] = (unsigned short)f2bf_rn(wr * v);
          }
        }
      }
  }
}

// ---------------------------------------------------------------- gather
__global__ void __launch_bounds__(256) gather_kernel(
    const float* __restrict__ x, const unsigned short* __restrict__ ybuf,
    const int* __restrict__ slot_of, float* __restrict__ out)
{
  const int b = blockIdx.x, t = threadIdx.x;
  int s[4];
#pragma unroll
  for (int k = 0; k < 4; k++) s[k] = slot_of[b * 4 + k];

  float4 xv = ((const float4*)(x + (size_t)b * D_))[t];
  float r0 = xv.x, r1 = xv.y, r2 = xv.z, r3 = xv.w;
#pragma unroll
  for (int k = 0; k < 4; k++) {
    uint2 p = ((const uint2*)(ybuf + (size_t)s[k] * D_))[t];
    r0 += bf2f(p.x & 0xffffu); r1 += bf2f(p.x >> 16);
    r2 += bf2f(p.y & 0xffffu); r3 += bf2f(p.y >> 16);
  }
  float4 o; o.x = r0; o.y = r1; o.z = r2; o.w = r3;
  ((float4*)(out + (size_t)b * D_))[t] = o;
}

// ---------------------------------------------------------------- launch
extern "C" void kernel_launch(void* const* d_in, const int* in_sizes, int n_in,
                              void* d_out, int out_size, void* d_ws, size_t ws_size,
                              hipStream_t stream)
{
  const float* x   = (const float*)d_in[0];
  const float* W1  = (const float*)d_in[1];
  const float* b1  = (const float*)d_in[2];
  const float* g1  = (const float*)d_in[3];
  const float* be1 = (const float*)d_in[4];
  const float* m1  = (const float*)d_in[5];
  const float* v1  = (const float*)d_in[6];
  const float* W2  = (const float*)d_in[7];
  const float* b2  = (const float*)d_in[8];
  const float* g2  = (const float*)d_in[9];
  const float* be2 = (const float*)d_in[10];
  const float* m2  = (const float*)d_in[11];
  const float* v2  = (const float*)d_in[12];
  const float* Wr  = (const float*)d_in[13];
  const float* br  = (const float*)d_in[14];
  float* out = (float*)d_out;

  char* ws = (char*)d_ws;
  int*            topi    = (int*)(ws + 0);
  float*          topw    = (float*)(ws + 32768);
  int*            slot_of = (int*)(ws + 65536);
  int*            tlist   = (int*)(ws + 98304);
  float*          wlist   = (float*)(ws + 131072);
  int*            counts  = (int*)(ws + 163840);
  int*            offs    = (int*)(ws + 164096);
  unsigned short* xbf     = (unsigned short*)(ws + 196608);
  unsigned short* hbuf    = (unsigned short*)(ws + 4390912);
  unsigned short* ybuf    = (unsigned short*)(ws + 29556736);

  router_kernel<<<dim3(B_), dim3(256), 0, stream>>>(x, Wr, br, topi, topw, xbf);
  setup_kernel<<<dim3(1), dim3(1024), 0, stream>>>(topi, topw, counts, offs, tlist, wlist, slot_of);
  gemm1_kernel<<<dim3(E_, 12), dim3(256), 0, stream>>>(xbf, W1, b1, g1, be1, m1, v1,
                                                       counts, offs, tlist, hbuf);
  gemm2_kernel<<<dim3(E_, 8), dim3(256), 0, stream>>>(hbuf, W2, b2, g2, be2, m2, v2,
                                                      counts, offs, wlist, ybuf);
  gather_kernel<<<dim3(B_), dim3(256), 0, stream>>>(x, ybuf, slot_of, out);
}